// Round 1
// baseline (215.144 us; speedup 1.0000x reference)
//
#include <hip/hip_runtime.h>
#include <hip/hip_bf16.h>
#include <math.h>

#define NSTEP 100
#define BATCH 16384
#define MB 16            // samples per wave == MFMA dim 16
#define NBLK (BATCH/MB)  // 1024 blocks x 1 wave -> 1 wave/SIMD, ZERO in-loop barriers
#define NT 64

#define C_ALPHA 0.05f
#define C_SIGMA 0.2f
#define C_THETA 0.3f
#define C_DT    0.01f
#define C_LOWER 1e-6f
#define C_PEN   100.0f
#define LOG2E   1.4426950408889634f
#define TSCALE  (2.0f * LOG2E)      // tanh(z) = 1 - 2/(exp2(TSCALE*z)+1)
#define CRT ( 0.015f * C_DT * LOG2E)
#define CRW ( 0.1f * LOG2E)
#define CPT (-0.095f * C_DT * LOG2E)
#define CPW (-0.3f * LOG2E)

typedef __attribute__((ext_vector_type(8))) short bf16x8;
typedef __attribute__((ext_vector_type(4))) float f32x4;

__device__ __forceinline__ float tanh_pre(float zs) {  // zs = TSCALE*z pre-folded
    float e = __builtin_amdgcn_exp2f(zs);
    return 1.0f - 2.0f * __builtin_amdgcn_rcpf(e + 1.0f);
}
__device__ __forceinline__ unsigned f2bf_u(float f) {  // RNE
    unsigned u = __float_as_uint(f);
    return (u + 0x7FFFu + ((u >> 16) & 1u)) >> 16;
}
__device__ __forceinline__ unsigned pack_bf16(float a, float b) {
    union { __hip_bfloat162 h; unsigned u; } cv;
    cv.h = __float22bfloat162_rn(make_float2(a, b));   // v_cvt_pk_bf16_f32
    return cv.u;
}
// sum across each 16-lane row via DPP row_ror butterfly; all lanes get the sum
__device__ __forceinline__ float dpp_row_sum16(float v) {
    int t;
    t = __builtin_amdgcn_update_dpp(0, __float_as_int(v), 0x128, 0xF, 0xF, true);
    v += __int_as_float(t);
    t = __builtin_amdgcn_update_dpp(0, __float_as_int(v), 0x124, 0xF, 0xF, true);
    v += __int_as_float(t);
    t = __builtin_amdgcn_update_dpp(0, __float_as_int(v), 0x122, 0xF, 0xF, true);
    v += __int_as_float(t);
    t = __builtin_amdgcn_update_dpp(0, __float_as_int(v), 0x121, 0xF, 0xF, true);
    v += __int_as_float(t);
    return v;
}

__global__ __launch_bounds__(NT, 1) void fused_kernel(
        const float* __restrict__ dw, const float* __restrict__ X0,
        const float* __restrict__ R0,
        const float* __restrict__ pW1, const float* __restrict__ pb1,
        const float* __restrict__ pW2, const float* __restrict__ pb2,
        const float* __restrict__ pW3, const float* __restrict__ pb3,
        const float* __restrict__ qW1, const float* __restrict__ qb1,
        const float* __restrict__ qW2, const float* __restrict__ qb2,
        const float* __restrict__ qW3, const float* __restrict__ qb3,
        float* __restrict__ ws, float* __restrict__ out) {
    __shared__ __align__(16) unsigned short sW2T[64 * 72];  // bf16 W2^T [n][k] *TSCALE
    __shared__ __align__(16) float sdw[MB * NSTEP];

    const int tid = threadIdx.x;
    const int lane = tid;                  // one wave per block
    const int b0 = blockIdx.x * MB;
    const int l15 = lane & 15, quad = lane >> 4;

    // ---- stage dw (coalesced float4) and W2^T (bf16, pre-scaled) ----
    {
        const float4* g = (const float4*)(dw + (size_t)b0 * NSTEP);
        float4* s = (float4*)sdw;
        for (int u = tid; u < MB * NSTEP / 4; u += NT) s[u] = g[u];
    }
    for (int u4 = tid; u4 < 1024; u4 += NT) {
        float4 w = ((const float4*)qW2)[u4];
        int base = u4 * 4;
        int k = base >> 6, n = base & 63;      // qW2[k*64+n] = W2[k][n]
        sW2T[(n + 0) * 72 + k] = (unsigned short)f2bf_u(w.x * TSCALE);
        sW2T[(n + 1) * 72 + k] = (unsigned short)f2bf_u(w.y * TSCALE);
        sW2T[(n + 2) * 72 + k] = (unsigned short)f2bf_u(w.z * TSCALE);
        sW2T[(n + 3) * 72 + k] = (unsigned short)f2bf_u(w.w * TSCALE);
    }
    __syncthreads();   // only barrier in the kernel (init staging)

    // resident W2^T fragments: ALL 4 n-tiles x 2 k-steps (used as MFMA *A* operand)
    // lane(q,c): W2T[n = nt*16 + c][k = ks*32 + q*8 + j]
    bf16x8 Bf[4][2];
    #pragma unroll
    for (int nt = 0; nt < 4; nt++) {
        const unsigned short* rp = &sW2T[(nt * 16 + l15) * 72 + quad * 8];
        Bf[nt][0] = *(const bf16x8*)rp;
        Bf[nt][1] = *(const bf16x8*)(rp + 32);
    }
    // layer-1 consts for this lane's 16 k's: k0 = quad*8+j (kstep0), k1 = 32+quad*8+j
    float tco[16], w1xs[16], w1rs[16], b1s[16];
    {
        const int kq = quad * 8;
        #pragma unroll
        for (int j = 0; j < 8; j++) {
            tco[j]      = qW1[kq + j]        * (2.0f * C_DT * TSCALE);
            tco[8 + j]  = qW1[32 + kq + j]   * (2.0f * C_DT * TSCALE);
            w1xs[j]     = qW1[64 + kq + j]   * TSCALE;
            w1xs[8 + j] = qW1[96 + kq + j]   * TSCALE;
            w1rs[j]     = qW1[128 + kq + j]  * TSCALE;
            w1rs[8 + j] = qW1[160 + kq + j]  * TSCALE;
            b1s[j]      = qb1[kq + j]        * TSCALE;
            b1s[8 + j]  = qb1[32 + kq + j]   * TSCALE;
        }
    }
    // swapped-output consts: acc[nt][r] = h2pre[n = nt*16 + quad*4 + r][sample l15]
    f32x4 b2a[4];
    float w3c[4][4];
    #pragma unroll
    for (int nt = 0; nt < 4; nt++) {
        #pragma unroll
        for (int r = 0; r < 4; r++) {
            b2a[nt][r] = qb2[nt * 16 + quad * 4 + r] * TSCALE;
            w3c[nt][r] = qW3[nt * 16 + quad * 4 + r];
        }
    }
    const float b3 = qb3[0];
    const float X0v = X0[0], R0s = R0[0];

    // ---- p-net: p0, dp0 (one-time) ----
    float p0, dp0;
    {
        float pre = fmaf(pW1[64 + lane], X0v, fmaf(pW1[128 + lane], R0s, pb1[lane]));
        float h1 = tanh_pre(TSCALE * pre);
        float d1 = (1.0f - h1 * h1) * pW1[64 + lane];
        float a0 = pb2[lane], a1 = 0.f, a2 = 0.f, a3 = 0.f;
        float e0 = 0.f, e1 = 0.f, e2 = 0.f, e3 = 0.f;
        for (int i2 = 0; i2 < 64; i2 += 4) {
            float w0 = pW2[(i2 + 0) * 64 + lane];
            float w1 = pW2[(i2 + 1) * 64 + lane];
            float w2 = pW2[(i2 + 2) * 64 + lane];
            float w3 = pW2[(i2 + 3) * 64 + lane];
            a0 = fmaf(__shfl(h1, i2 + 0), w0, a0); e0 = fmaf(__shfl(d1, i2 + 0), w0, e0);
            a1 = fmaf(__shfl(h1, i2 + 1), w1, a1); e1 = fmaf(__shfl(d1, i2 + 1), w1, e1);
            a2 = fmaf(__shfl(h1, i2 + 2), w2, a2); e2 = fmaf(__shfl(d1, i2 + 2), w2, e2);
            a3 = fmaf(__shfl(h1, i2 + 3), w3, a3); e3 = fmaf(__shfl(d1, i2 + 3), w3, e3);
        }
        float pre2 = (a0 + a1) + (a2 + a3);
        float dpre2 = (e0 + e1) + (e2 + e3);
        float h2 = tanh_pre(TSCALE * pre2);
        float d2 = (1.0f - h2 * h2) * dpre2;
        float c1 = h2 * pW3[lane], c2 = d2 * pW3[lane];
        #pragma unroll
        for (int o = 1; o < 64; o <<= 1) {
            c1 += __shfl_xor(c1, o);
            c2 += __shfl_xor(c2, o);
        }
        p0 = c1 + pb3[0]; dp0 = c2;
    }

    // ---- single-wave q-net: no barriers, pi returned on ALL lanes ----
    auto qnet = [&](float fi, float xv, float rv) -> float {
        union { bf16x8 v; unsigned u[4]; } A0u, A1u;
        #pragma unroll
        for (int p = 0; p < 4; p++) {
            const int i0 = 2 * p, i1 = 2 * p + 1;
            float z0 = fmaf(w1rs[i0], rv, fmaf(w1xs[i0], xv, fmaf(tco[i0], fi, b1s[i0])));
            float z1 = fmaf(w1rs[i1], rv, fmaf(w1xs[i1], xv, fmaf(tco[i1], fi, b1s[i1])));
            A0u.u[p] = pack_bf16(tanh_pre(z0), tanh_pre(z1));
            float z2 = fmaf(w1rs[8 + i0], rv, fmaf(w1xs[8 + i0], xv, fmaf(tco[8 + i0], fi, b1s[8 + i0])));
            float z3 = fmaf(w1rs[8 + i1], rv, fmaf(w1xs[8 + i1], xv, fmaf(tco[8 + i1], fi, b1s[8 + i1])));
            A1u.u[p] = pack_bf16(tanh_pre(z2), tanh_pre(z3));
        }
        // swapped operands: D[row = n-within-tile][col = SAMPLE = lane&15]
        float ps0 = 0.f, ps1 = 0.f, ps2 = 0.f, ps3 = 0.f;
        #pragma unroll
        for (int nt = 0; nt < 4; nt++) {
            f32x4 a = b2a[nt];
            a = __builtin_amdgcn_mfma_f32_16x16x32_bf16(Bf[nt][0], A0u.v, a, 0, 0, 0);
            a = __builtin_amdgcn_mfma_f32_16x16x32_bf16(Bf[nt][1], A1u.v, a, 0, 0, 0);
            ps0 = fmaf(tanh_pre(a[0]), w3c[nt][0], ps0);
            ps1 = fmaf(tanh_pre(a[1]), w3c[nt][1], ps1);
            ps2 = fmaf(tanh_pre(a[2]), w3c[nt][2], ps2);
            ps3 = fmaf(tanh_pre(a[3]), w3c[nt][3], ps3);
        }
        float ps = (ps0 + ps1) + (ps2 + ps3);   // 16 of 64 n-terms (this quad's rows)
        ps += __shfl_xor(ps, 16);               // cross-quad tree: all 64 n-terms
        ps += __shfl_xor(ps, 32);
        return ps + b3;
    };

    // ---- t=0 row + initial pi ----
    float x = X0v, Wsum = 0.0f, minx = X0v;
    float pi = qnet(0.0f, X0v, R0s);
    if (quad == 0) {
        size_t base = (size_t)(b0 + l15) * 5;
        out[base] = X0v; out[base + 1] = R0s; out[base + 2] = pi;
        out[base + 3] = -p0; out[base + 4] = -dp0;
    }

    float dw_next = sdw[l15 * NSTEP];
    #pragma unroll 1
    for (int i = 0; i < NSTEP - 1; i++) {
        const float fi = (float)(i + 1);
        float dwv = dw_next;
        dw_next = sdw[l15 * NSTEP + i + 1];
        float t = pi * C_SIGMA;
        x = fmaf(x, 1.0f + C_ALPHA * C_DT, fmaf(t, dwv, t * (C_THETA * C_DT)));
        minx = fminf(minx, x);
        Wsum += dwv;
        float R = R0s * __builtin_amdgcn_exp2f(fmaf(CRW, Wsum, CRT * fi));
        float pm = p0 * __builtin_amdgcn_exp2f(fmaf(CPW, Wsum, CPT * fi));
        float pin = qnet(fi, x, R);
        if (quad == 0) {
            size_t base = ((size_t)(i + 1) * BATCH + b0 + l15) * 5;
            out[base] = x; out[base + 1] = R; out[base + 2] = pin;
            out[base + 3] = -pm; out[base + 4] = -dp0;
        }
        pi = pin;
    }

    // ---- final step (pi not updated) + losses ----
    {
        float dwv = dw_next;
        float t = pi * C_SIGMA;
        x = fmaf(x, 1.0f + C_ALPHA * C_DT, fmaf(t, dwv, t * (C_THETA * C_DT)));
        minx = fminf(minx, x);
        Wsum += dwv;
        float Rf = R0s * __builtin_amdgcn_exp2f(fmaf(CRW, Wsum, CRT * (float)NSTEP));
        float pf = p0 * __builtin_amdgcn_exp2f(fmaf(CPW, Wsum, CPT * (float)NSTEP));
        if (quad == 0) {
            size_t base = ((size_t)NSTEP * BATCH + b0 + l15) * 5;
            out[base] = x; out[base + 1] = Rf; out[base + 2] = pi;
            out[base + 3] = -pf; out[base + 4] = -dp0;
        }
        // losses: values replicated across quads, so each 16-lane row sums all 16 samples
        float xc = fmaxf(x, C_LOWER);
        float ux = Rf * rsqrtf(xc);           // R * xc^(gamma-1), gamma=0.5
        float uval = 2.0f * Rf * sqrtf(xc);   // R * xc^gamma / gamma
        float d = fmaxf(C_LOWER - minx, 0.0f);
        float pen = C_PEN * d * d;
        float t1 = pf + ux;
        float v1 = dpp_row_sum16(t1 * t1 + pen);
        float v2 = dpp_row_sum16(-uval + pen);
        if (lane == 0) {
            atomicAdd(&ws[3], v1);
            atomicAdd(&ws[4], v2);
            __threadfence();
            int old = atomicAdd((int*)(ws + 5), 1);
            if (old == NBLK - 1) {   // last block finalizes losses
                float lp = atomicAdd(&ws[3], 0.0f) * (1.0f / (float)BATCH);
                float lq = atomicAdd(&ws[4], 0.0f) * (1.0f / (float)BATCH);
                out[(size_t)(NSTEP + 1) * BATCH * 5] = lp;
                out[(size_t)(NSTEP + 1) * BATCH * 5 + 1] = lp + lq;
            }
        }
    }
}

extern "C" void kernel_launch(void* const* d_in, const int* in_sizes, int n_in,
                              void* d_out, int out_size, void* d_ws, size_t ws_size,
                              hipStream_t stream) {
    const float* dw  = (const float*)d_in[0];
    const float* X0  = (const float*)d_in[1];
    const float* R0  = (const float*)d_in[2];
    const float* pW1 = (const float*)d_in[3];
    const float* pb1 = (const float*)d_in[4];
    const float* pW2 = (const float*)d_in[5];
    const float* pb2 = (const float*)d_in[6];
    const float* pW3 = (const float*)d_in[7];
    const float* pb3 = (const float*)d_in[8];
    const float* qW1 = (const float*)d_in[9];
    const float* qb1 = (const float*)d_in[10];
    const float* qW2 = (const float*)d_in[11];
    const float* qb2 = (const float*)d_in[12];
    const float* qW3 = (const float*)d_in[13];
    const float* qb3 = (const float*)d_in[14];
    float* out = (float*)d_out;
    float* ws  = (float*)d_ws;

    hipMemsetAsync(d_ws, 0, 64, stream);   // zero loss accumulators + block counter
    fused_kernel<<<NBLK, NT, 0, stream>>>(dw, X0, R0, pW1, pb1, pW2, pb2, pW3, pb3,
                                          qW1, qb1, qW2, qb2, qW3, qb3, ws, out);
}

// Round 2
// 209.003 us; speedup vs baseline: 1.0294x; 1.0294x over previous
//
#include <hip/hip_runtime.h>
#include <hip/hip_bf16.h>
#include <math.h>

#define NSTEP 100
#define BATCH 16384
#define MB 16            // samples per block == MFMA M
#define NBLK (BATCH/MB)  // 1024 blocks x 2 waves = 2048 waves -> 2/SIMD
#define NT 128

#define C_ALPHA 0.05f
#define C_SIGMA 0.2f
#define C_THETA 0.3f
#define C_DT    0.01f
#define C_LOWER 1e-6f
#define C_PEN   100.0f
#define LOG2E   1.4426950408889634f
#define TSCALE  (2.0f * LOG2E)      // tanh(z) = 1 - 2/(exp2(TSCALE*z)+1)
#define CRT ( 0.015f * C_DT * LOG2E)
#define CRW ( 0.1f * LOG2E)
#define CPT (-0.095f * C_DT * LOG2E)
#define CPW (-0.3f * LOG2E)

// Cross-wave LDS sync WITHOUT the vmcnt(0) drain __syncthreads() implies:
// only LDS ops must be complete/visible; global stores stay in flight.
#define WG_BARRIER() asm volatile("s_waitcnt lgkmcnt(0)\n\ts_barrier" ::: "memory")

typedef __attribute__((ext_vector_type(8))) short bf16x8;
typedef __attribute__((ext_vector_type(4))) float f32x4;

__device__ __forceinline__ float tanh_pre(float zs) {  // zs = TSCALE*z pre-folded
    float e = __builtin_amdgcn_exp2f(zs);
    return 1.0f - 2.0f * __builtin_amdgcn_rcpf(e + 1.0f);
}
__device__ __forceinline__ unsigned f2bf_u(float f) {  // RNE
    unsigned u = __float_as_uint(f);
    return (u + 0x7FFFu + ((u >> 16) & 1u)) >> 16;
}
__device__ __forceinline__ unsigned pack_bf16(float a, float b) {
    union { __hip_bfloat162 h; unsigned u; } cv;
    cv.h = __float22bfloat162_rn(make_float2(a, b));   // v_cvt_pk_bf16_f32
    return cv.u;
}
// sum across each 16-lane row via DPP row_ror butterfly; all lanes get the sum
__device__ __forceinline__ float dpp_row_sum16(float v) {
    int t;
    t = __builtin_amdgcn_update_dpp(0, __float_as_int(v), 0x128, 0xF, 0xF, true);
    v += __int_as_float(t);
    t = __builtin_amdgcn_update_dpp(0, __float_as_int(v), 0x124, 0xF, 0xF, true);
    v += __int_as_float(t);
    t = __builtin_amdgcn_update_dpp(0, __float_as_int(v), 0x122, 0xF, 0xF, true);
    v += __int_as_float(t);
    t = __builtin_amdgcn_update_dpp(0, __float_as_int(v), 0x121, 0xF, 0xF, true);
    v += __int_as_float(t);
    return v;
}

__global__ __launch_bounds__(NT, 2) void fused_kernel(
        const float* __restrict__ dw, const float* __restrict__ X0,
        const float* __restrict__ R0,
        const float* __restrict__ pW1, const float* __restrict__ pb1,
        const float* __restrict__ pW2, const float* __restrict__ pb2,
        const float* __restrict__ pW3, const float* __restrict__ pb3,
        const float* __restrict__ qW1, const float* __restrict__ qb1,
        const float* __restrict__ qW2, const float* __restrict__ qb2,
        const float* __restrict__ qW3, const float* __restrict__ qb3,
        float* __restrict__ ws, float* __restrict__ out) {
    __shared__ __align__(16) unsigned short sW2T[64 * 72];  // bf16 W2^T [n][k] *TSCALE
    __shared__ __align__(16) float sdw[MB * NSTEP];
    __shared__ __align__(16) uint4 sA[2][2][64];   // [parity][kstep-owner wave][lane]
    __shared__ __align__(16) float sP[2][2][16];   // [parity][wave][sample]

    const int tid = threadIdx.x;
    const int lane = tid & 63;
    const int wv = tid >> 6;               // wave 0/1: n-half + kstep-half owner
    const int b0 = blockIdx.x * MB;
    const int l15 = lane & 15, quad = lane >> 4;

    // ---- stage dw (coalesced float4) and W2^T (bf16, pre-scaled) ----
    {
        const float4* g = (const float4*)(dw + (size_t)b0 * NSTEP);
        float4* s = (float4*)sdw;
        #pragma unroll
        for (int u = tid; u < MB * NSTEP / 4; u += NT) s[u] = g[u];
    }
    for (int u = tid; u < 4096; u += NT) {
        int k = u >> 6, n = u & 63;
        sW2T[n * 72 + k] = (unsigned short)f2bf_u(qW2[u] * TSCALE);
    }
    __syncthreads();

    // resident B fragments: this wave's 2 n-tiles x 2 k-steps
    bf16x8 Bf[2][2];
    #pragma unroll
    for (int t = 0; t < 2; t++) {
        const unsigned short* r = &sW2T[(wv * 32 + t * 16 + l15) * 72 + quad * 8];
        Bf[t][0] = *(const bf16x8*)r;
        Bf[t][1] = *(const bf16x8*)(r + 32);
    }
    // layer-1 consts: this wave's 8 k's (kstep = wv)
    float tco[8], w1xs[8], w1rs[8], b1s[8];
    #pragma unroll
    for (int j = 0; j < 8; j++) {
        int k = wv * 32 + quad * 8 + j;
        tco[j]  = qW1[k] * (2.0f * C_DT * TSCALE);
        w1xs[j] = qW1[64 + k] * TSCALE;
        w1rs[j] = qW1[128 + k] * TSCALE;
        b1s[j]  = qb1[k] * TSCALE;
    }
    float b2v[2], w3v[2];
    #pragma unroll
    for (int t = 0; t < 2; t++) {
        b2v[t] = qb2[wv * 32 + t * 16 + l15] * TSCALE;
        w3v[t] = qW3[wv * 32 + t * 16 + l15];
    }
    const float b3 = qb3[0];
    const float X0v = X0[0], R0s = R0[0];

    // ---- p-net: p0, dp0 (one-time; computed redundantly per wave) ----
    float p0, dp0;
    {
        float pre = fmaf(pW1[64 + lane], X0v, fmaf(pW1[128 + lane], R0s, pb1[lane]));
        float h1 = tanh_pre(TSCALE * pre);
        float d1 = (1.0f - h1 * h1) * pW1[64 + lane];
        float a0 = pb2[lane], a1 = 0.f, a2 = 0.f, a3 = 0.f;
        float e0 = 0.f, e1 = 0.f, e2 = 0.f, e3 = 0.f;
        for (int i2 = 0; i2 < 64; i2 += 4) {
            float w0 = pW2[(i2 + 0) * 64 + lane];
            float w1 = pW2[(i2 + 1) * 64 + lane];
            float w2 = pW2[(i2 + 2) * 64 + lane];
            float w3 = pW2[(i2 + 3) * 64 + lane];
            a0 = fmaf(__shfl(h1, i2 + 0), w0, a0); e0 = fmaf(__shfl(d1, i2 + 0), w0, e0);
            a1 = fmaf(__shfl(h1, i2 + 1), w1, a1); e1 = fmaf(__shfl(d1, i2 + 1), w1, e1);
            a2 = fmaf(__shfl(h1, i2 + 2), w2, a2); e2 = fmaf(__shfl(d1, i2 + 2), w2, e2);
            a3 = fmaf(__shfl(h1, i2 + 3), w3, a3); e3 = fmaf(__shfl(d1, i2 + 3), w3, e3);
        }
        float pre2 = (a0 + a1) + (a2 + a3);
        float dpre2 = (e0 + e1) + (e2 + e3);
        float h2 = tanh_pre(TSCALE * pre2);
        float d2 = (1.0f - h2 * h2) * dpre2;
        float c1 = h2 * pW3[lane], c2 = d2 * pW3[lane];
        #pragma unroll
        for (int o = 1; o < 64; o <<= 1) {
            c1 += __shfl_xor(c1, o);
            c2 += __shfl_xor(c2, o);
        }
        p0 = c1 + pb3[0]; dp0 = c2;
    }

    // ---- cooperative q-net: 2 waves split n & k; pi returned on ALL lanes ----
    // Per-step sync is raw s_barrier + lgkmcnt(0) only (no vmcnt drain: global
    // out-stores from previous steps stay in flight across the exchange).
    auto qnet = [&](int par, float fi, float xv, float rv) -> float {
        union { uint4 u4; bf16x8 v; unsigned u[4]; } Aloc, Aoth;
        #pragma unroll
        for (int p = 0; p < 4; p++) {
            const int i0 = 2 * p, i1 = 2 * p + 1;
            float z0 = fmaf(w1rs[i0], rv, fmaf(w1xs[i0], xv, fmaf(tco[i0], fi, b1s[i0])));
            float z1 = fmaf(w1rs[i1], rv, fmaf(w1xs[i1], xv, fmaf(tco[i1], fi, b1s[i1])));
            Aloc.u[p] = pack_bf16(tanh_pre(z0), tanh_pre(z1));
        }
        sA[par][wv][lane] = Aloc.u4;
        WG_BARRIER();                          // B1: A halves exchanged (LDS only)
        Aoth.u4 = sA[par][1 - wv][lane];
        bf16x8 A0 = (wv == 0) ? Aloc.v : Aoth.v;   // kstep 0 frag
        bf16x8 A1 = (wv == 0) ? Aoth.v : Aloc.v;   // kstep 1 frag
        f32x4 acc0 = {b2v[0], b2v[0], b2v[0], b2v[0]};
        f32x4 acc1 = {b2v[1], b2v[1], b2v[1], b2v[1]};
        acc0 = __builtin_amdgcn_mfma_f32_16x16x32_bf16(A0, Bf[0][0], acc0, 0, 0, 0);
        acc1 = __builtin_amdgcn_mfma_f32_16x16x32_bf16(A0, Bf[1][0], acc1, 0, 0, 0);
        acc0 = __builtin_amdgcn_mfma_f32_16x16x32_bf16(A1, Bf[0][1], acc0, 0, 0, 0);
        acc1 = __builtin_amdgcn_mfma_f32_16x16x32_bf16(A1, Bf[1][1], acc1, 0, 0, 0);
        f32x4 part;
        #pragma unroll
        for (int r = 0; r < 4; r++)
            part[r] = dpp_row_sum16(
                fmaf(tanh_pre(acc1[r]), w3v[1], tanh_pre(acc0[r]) * w3v[0]));
        if (l15 == 0) *(f32x4*)&sP[par][wv][quad * 4] = part;  // samples 4q+r
        WG_BARRIER();                          // B2: partials exchanged (LDS only)
        return sP[par][0][l15] + sP[par][1][l15] + b3;
    };

    // ---- t=0 row + initial pi ----
    float x = X0v, Wsum = 0.0f, minx = X0v;
    float pi = qnet(0, 0.0f, X0v, R0s);
    if (wv == 1 && quad == 0) {
        size_t base = (size_t)(b0 + l15) * 5;
        out[base] = X0v; out[base + 1] = R0s; out[base + 2] = pi;
        out[base + 3] = -p0; out[base + 4] = -dp0;
    }

    float dw_next = sdw[l15 * NSTEP];
    #pragma unroll 1
    for (int i = 0; i < NSTEP - 1; i++) {
        const float fi = (float)(i + 1);
        float dwv = dw_next;
        dw_next = sdw[l15 * NSTEP + i + 1];
        float t = pi * C_SIGMA;
        x = fmaf(x, 1.0f + C_ALPHA * C_DT, fmaf(t, dwv, t * (C_THETA * C_DT)));
        minx = fminf(minx, x);
        Wsum += dwv;
        float R = R0s * __builtin_amdgcn_exp2f(fmaf(CRW, Wsum, CRT * fi));
        float pm = p0 * __builtin_amdgcn_exp2f(fmaf(CPW, Wsum, CPT * fi));
        float pin = qnet((i + 1) & 1, fi, x, R);
        if (wv == 1 && quad == 0) {
            size_t base = ((size_t)(i + 1) * BATCH + b0 + l15) * 5;
            out[base] = x; out[base + 1] = R; out[base + 2] = pin;
            out[base + 3] = -pm; out[base + 4] = -dp0;
        }
        pi = pin;
    }

    // ---- final step (pi not updated) + losses ----
    {
        float dwv = dw_next;
        float t = pi * C_SIGMA;
        x = fmaf(x, 1.0f + C_ALPHA * C_DT, fmaf(t, dwv, t * (C_THETA * C_DT)));
        minx = fminf(minx, x);
        Wsum += dwv;
        float Rf = R0s * __builtin_amdgcn_exp2f(fmaf(CRW, Wsum, CRT * (float)NSTEP));
        float pf = p0 * __builtin_amdgcn_exp2f(fmaf(CPW, Wsum, CPT * (float)NSTEP));
        if (wv == 1 && quad == 0) {
            size_t base = ((size_t)NSTEP * BATCH + b0 + l15) * 5;
            out[base] = x; out[base + 1] = Rf; out[base + 2] = pi;
            out[base + 3] = -pf; out[base + 4] = -dp0;
        }
        if (wv == 0) {
            float xc = fmaxf(x, C_LOWER);
            float ux = Rf * rsqrtf(xc);           // R * xc^(gamma-1), gamma=0.5
            float uval = 2.0f * Rf * sqrtf(xc);   // R * xc^gamma / gamma
            float d = fmaxf(C_LOWER - minx, 0.0f);
            float pen = C_PEN * d * d;
            float t1 = pf + ux;
            float v1 = dpp_row_sum16(t1 * t1 + pen);
            float v2 = dpp_row_sum16(-uval + pen);
            if (lane == 0) {
                atomicAdd(&ws[3], v1);
                atomicAdd(&ws[4], v2);
                __threadfence();
                int old = atomicAdd((int*)(ws + 5), 1);
                if (old == NBLK - 1) {   // last block finalizes losses
                    float lp = atomicAdd(&ws[3], 0.0f) * (1.0f / (float)BATCH);
                    float lq = atomicAdd(&ws[4], 0.0f) * (1.0f / (float)BATCH);
                    out[(size_t)(NSTEP + 1) * BATCH * 5] = lp;
                    out[(size_t)(NSTEP + 1) * BATCH * 5 + 1] = lp + lq;
                }
            }
        }
    }
}

extern "C" void kernel_launch(void* const* d_in, const int* in_sizes, int n_in,
                              void* d_out, int out_size, void* d_ws, size_t ws_size,
                              hipStream_t stream) {
    const float* dw  = (const float*)d_in[0];
    const float* X0  = (const float*)d_in[1];
    const float* R0  = (const float*)d_in[2];
    const float* pW1 = (const float*)d_in[3];
    const float* pb1 = (const float*)d_in[4];
    const float* pW2 = (const float*)d_in[5];
    const float* pb2 = (const float*)d_in[6];
    const float* pW3 = (const float*)d_in[7];
    const float* pb3 = (const float*)d_in[8];
    const float* qW1 = (const float*)d_in[9];
    const float* qb1 = (const float*)d_in[10];
    const float* qW2 = (const float*)d_in[11];
    const float* qb2 = (const float*)d_in[12];
    const float* qW3 = (const float*)d_in[13];
    const float* qb3 = (const float*)d_in[14];
    float* out = (float*)d_out;
    float* ws  = (float*)d_ws;

    hipMemsetAsync(d_ws, 0, 64, stream);   // zero loss accumulators + block counter
    fused_kernel<<<NBLK, NT, 0, stream>>>(dw, X0, R0, pW1, pb1, pW2, pb2, pW3, pb3,
                                          qW1, qb1, qW2, qb2, qW3, qb3, ws, out);
}

// Round 3
// 206.446 us; speedup vs baseline: 1.0421x; 1.0124x over previous
//
#include <hip/hip_runtime.h>
#include <hip/hip_bf16.h>
#include <math.h>

#define NSTEP 100
#define BATCH 16384
#define MB 16            // samples per block == MFMA M
#define NBLK (BATCH/MB)  // 1024 blocks x 2 waves = 2048 waves -> 2/SIMD
#define NT 128

#define C_ALPHA 0.05f
#define C_SIGMA 0.2f
#define C_THETA 0.3f
#define C_DT    0.01f
#define C_LOWER 1e-6f
#define C_PEN   100.0f
#define LOG2E   1.4426950408889634f
#define TSCALE  (2.0f * LOG2E)      // tanh(z) = 1 - 2/(exp2(TSCALE*z)+1)
#define CRT ( 0.015f * C_DT * LOG2E)
#define CRW ( 0.1f * LOG2E)
#define CPT (-0.095f * C_DT * LOG2E)
#define CPW (-0.3f * LOG2E)

// Cross-wave LDS sync WITHOUT the vmcnt(0) drain __syncthreads() implies:
// only LDS ops must be complete/visible; global stores stay in flight.
#define WG_BARRIER() asm volatile("s_waitcnt lgkmcnt(0)\n\ts_barrier" ::: "memory")

typedef __attribute__((ext_vector_type(8))) short bf16x8;
typedef __attribute__((ext_vector_type(4))) float f32x4;
// 4-byte-aligned float4 for the packed out-row store (rows are 20B apart)
typedef __attribute__((ext_vector_type(4), aligned(4))) float f32x4a;

__device__ __forceinline__ float tanh_pre(float zs) {  // zs = TSCALE*z pre-folded
    float e = __builtin_amdgcn_exp2f(zs);
    return 1.0f - 2.0f * __builtin_amdgcn_rcpf(e + 1.0f);
}
__device__ __forceinline__ unsigned f2bf_u(float f) {  // RNE
    unsigned u = __float_as_uint(f);
    return (u + 0x7FFFu + ((u >> 16) & 1u)) >> 16;
}
__device__ __forceinline__ unsigned pack_bf16(float a, float b) {
    union { __hip_bfloat162 h; unsigned u; } cv;
    cv.h = __float22bfloat162_rn(make_float2(a, b));   // v_cvt_pk_bf16_f32
    return cv.u;
}
// sum across each 16-lane row via DPP row_ror butterfly; all lanes get the sum
__device__ __forceinline__ float dpp_row_sum16(float v) {
    int t;
    t = __builtin_amdgcn_update_dpp(0, __float_as_int(v), 0x128, 0xF, 0xF, true);
    v += __int_as_float(t);
    t = __builtin_amdgcn_update_dpp(0, __float_as_int(v), 0x124, 0xF, 0xF, true);
    v += __int_as_float(t);
    t = __builtin_amdgcn_update_dpp(0, __float_as_int(v), 0x122, 0xF, 0xF, true);
    v += __int_as_float(t);
    t = __builtin_amdgcn_update_dpp(0, __float_as_int(v), 0x121, 0xF, 0xF, true);
    v += __int_as_float(t);
    return v;
}

__global__ __launch_bounds__(NT, 2) void fused_kernel(
        const float* __restrict__ dw, const float* __restrict__ X0,
        const float* __restrict__ R0,
        const float* __restrict__ pW1, const float* __restrict__ pb1,
        const float* __restrict__ pW2, const float* __restrict__ pb2,
        const float* __restrict__ pW3, const float* __restrict__ pb3,
        const float* __restrict__ qW1, const float* __restrict__ qb1,
        const float* __restrict__ qW2, const float* __restrict__ qb2,
        const float* __restrict__ qW3, const float* __restrict__ qb3,
        float* __restrict__ ws, float* __restrict__ out) {
    __shared__ __align__(16) unsigned short sW2T[64 * 72];  // bf16 W2^T [n][k] *TSCALE
    __shared__ __align__(16) float sdw[MB * NSTEP];
    __shared__ __align__(16) uint4 sA[2][2][64];   // [parity][kstep-owner wave][lane]
    __shared__ __align__(16) float sP[2][2][16];   // [parity][wave][sample]

    const int tid = threadIdx.x;
    const int lane = tid & 63;
    const int wv = tid >> 6;               // wave 0/1: n-half + kstep-half owner
    const int b0 = blockIdx.x * MB;
    const int l15 = lane & 15, quad = lane >> 4;

    // ---- stage dw (coalesced float4) and W2^T (bf16, pre-scaled) ----
    {
        const float4* g = (const float4*)(dw + (size_t)b0 * NSTEP);
        float4* s = (float4*)sdw;
        #pragma unroll
        for (int u = tid; u < MB * NSTEP / 4; u += NT) s[u] = g[u];
    }
    for (int u = tid; u < 4096; u += NT) {
        int k = u >> 6, n = u & 63;
        sW2T[n * 72 + k] = (unsigned short)f2bf_u(qW2[u] * TSCALE);
    }
    __syncthreads();

    // resident B fragments: this wave's 2 n-tiles x 2 k-steps
    bf16x8 Bf[2][2];
    #pragma unroll
    for (int t = 0; t < 2; t++) {
        const unsigned short* r = &sW2T[(wv * 32 + t * 16 + l15) * 72 + quad * 8];
        Bf[t][0] = *(const bf16x8*)r;
        Bf[t][1] = *(const bf16x8*)(r + 32);
    }
    // layer-1 consts: this wave's 8 k's (kstep = wv)
    float tco[8], w1xs[8], w1rs[8], b1s[8];
    #pragma unroll
    for (int j = 0; j < 8; j++) {
        int k = wv * 32 + quad * 8 + j;
        tco[j]  = qW1[k] * (2.0f * C_DT * TSCALE);
        w1xs[j] = qW1[64 + k] * TSCALE;
        w1rs[j] = qW1[128 + k] * TSCALE;
        b1s[j]  = qb1[k] * TSCALE;
    }
    float b2v[2], w3v[2];
    #pragma unroll
    for (int t = 0; t < 2; t++) {
        b2v[t] = qb2[wv * 32 + t * 16 + l15] * TSCALE;
        w3v[t] = qW3[wv * 32 + t * 16 + l15];
    }
    const float b3 = qb3[0];
    const float X0v = X0[0], R0s = R0[0];

    // ---- p-net: p0, dp0 (one-time; computed redundantly per wave) ----
    float p0, dp0;
    {
        float pre = fmaf(pW1[64 + lane], X0v, fmaf(pW1[128 + lane], R0s, pb1[lane]));
        float h1 = tanh_pre(TSCALE * pre);
        float d1 = (1.0f - h1 * h1) * pW1[64 + lane];
        float a0 = pb2[lane], a1 = 0.f, a2 = 0.f, a3 = 0.f;
        float e0 = 0.f, e1 = 0.f, e2 = 0.f, e3 = 0.f;
        for (int i2 = 0; i2 < 64; i2 += 4) {
            float w0 = pW2[(i2 + 0) * 64 + lane];
            float w1 = pW2[(i2 + 1) * 64 + lane];
            float w2 = pW2[(i2 + 2) * 64 + lane];
            float w3 = pW2[(i2 + 3) * 64 + lane];
            a0 = fmaf(__shfl(h1, i2 + 0), w0, a0); e0 = fmaf(__shfl(d1, i2 + 0), w0, e0);
            a1 = fmaf(__shfl(h1, i2 + 1), w1, a1); e1 = fmaf(__shfl(d1, i2 + 1), w1, e1);
            a2 = fmaf(__shfl(h1, i2 + 2), w2, a2); e2 = fmaf(__shfl(d1, i2 + 2), w2, e2);
            a3 = fmaf(__shfl(h1, i2 + 3), w3, a3); e3 = fmaf(__shfl(d1, i2 + 3), w3, e3);
        }
        float pre2 = (a0 + a1) + (a2 + a3);
        float dpre2 = (e0 + e1) + (e2 + e3);
        float h2 = tanh_pre(TSCALE * pre2);
        float d2 = (1.0f - h2 * h2) * dpre2;
        float c1 = h2 * pW3[lane], c2 = d2 * pW3[lane];
        #pragma unroll
        for (int o = 1; o < 64; o <<= 1) {
            c1 += __shfl_xor(c1, o);
            c2 += __shfl_xor(c2, o);
        }
        p0 = c1 + pb3[0]; dp0 = c2;
    }
    const float mdp0 = -dp0;   // loop-invariant store source: never needs a vmcnt wait

    // ---- cooperative q-net: 2 waves split n & k; pi returned on ALL lanes ----
    auto qnet = [&](int par, float fi, float xv, float rv) -> float {
        union { uint4 u4; bf16x8 v; unsigned u[4]; } Aloc, Aoth;
        #pragma unroll
        for (int p = 0; p < 4; p++) {
            const int i0 = 2 * p, i1 = 2 * p + 1;
            float z0 = fmaf(w1rs[i0], rv, fmaf(w1xs[i0], xv, fmaf(tco[i0], fi, b1s[i0])));
            float z1 = fmaf(w1rs[i1], rv, fmaf(w1xs[i1], xv, fmaf(tco[i1], fi, b1s[i1])));
            Aloc.u[p] = pack_bf16(tanh_pre(z0), tanh_pre(z1));
        }
        sA[par][wv][lane] = Aloc.u4;
        WG_BARRIER();                          // B1: A halves exchanged (LDS only)
        Aoth.u4 = sA[par][1 - wv][lane];
        bf16x8 A0 = (wv == 0) ? Aloc.v : Aoth.v;   // kstep 0 frag
        bf16x8 A1 = (wv == 0) ? Aoth.v : Aloc.v;   // kstep 1 frag
        f32x4 acc0 = {b2v[0], b2v[0], b2v[0], b2v[0]};
        f32x4 acc1 = {b2v[1], b2v[1], b2v[1], b2v[1]};
        acc0 = __builtin_amdgcn_mfma_f32_16x16x32_bf16(A0, Bf[0][0], acc0, 0, 0, 0);
        acc1 = __builtin_amdgcn_mfma_f32_16x16x32_bf16(A0, Bf[1][0], acc1, 0, 0, 0);
        acc0 = __builtin_amdgcn_mfma_f32_16x16x32_bf16(A1, Bf[0][1], acc0, 0, 0, 0);
        acc1 = __builtin_amdgcn_mfma_f32_16x16x32_bf16(A1, Bf[1][1], acc1, 0, 0, 0);
        f32x4 part;
        #pragma unroll
        for (int r = 0; r < 4; r++)
            part[r] = dpp_row_sum16(
                fmaf(tanh_pre(acc1[r]), w3v[1], tanh_pre(acc0[r]) * w3v[0]));
        if (l15 == 0) *(f32x4*)&sP[par][wv][quad * 4] = part;  // samples 4q+r
        WG_BARRIER();                          // B2: partials exchanged (LDS only)
        return sP[par][0][l15] + sP[par][1][l15] + b3;
    };

    // ---- t=0 row + initial pi ----
    float x = X0v, Wsum = 0.0f, minx = X0v;
    float pi = qnet(0, 0.0f, X0v, R0s);
    if (wv == 1) {
        size_t base = (size_t)(b0 + l15) * 5;
        if (quad == 0) {
            f32x4a o = {X0v, R0s, pi, -p0};
            *(f32x4a*)(out + base) = o;        // one dwordx4 instead of 4 dwords
        } else if (quad == 1) {
            out[base + 4] = mdp0;              // invariant source register
        }
    }

    float dw_next = sdw[l15 * NSTEP];
    // unroll 2: distinct SSA registers per copy -> store-source registers are
    // not rewritten until 2 iterations later; vmcnt drain overlaps a full step.
    #pragma unroll 2
    for (int i = 0; i < NSTEP - 1; i++) {
        const float fi = (float)(i + 1);
        float dwv = dw_next;
        dw_next = sdw[l15 * NSTEP + i + 1];
        float t = pi * C_SIGMA;
        x = fmaf(x, 1.0f + C_ALPHA * C_DT, fmaf(t, dwv, t * (C_THETA * C_DT)));
        minx = fminf(minx, x);
        Wsum += dwv;
        float R = R0s * __builtin_amdgcn_exp2f(fmaf(CRW, Wsum, CRT * fi));
        float pm = p0 * __builtin_amdgcn_exp2f(fmaf(CPW, Wsum, CPT * fi));
        float pin = qnet((i + 1) & 1, fi, x, R);
        if (wv == 1) {
            size_t base = ((size_t)(i + 1) * BATCH + b0 + l15) * 5;
            if (quad == 0) {
                f32x4a o = {x, R, pin, -pm};
                *(f32x4a*)(out + base) = o;
            } else if (quad == 1) {
                out[base + 4] = mdp0;
            }
        }
        pi = pin;
    }

    // ---- final step (pi not updated) + losses ----
    {
        float dwv = dw_next;
        float t = pi * C_SIGMA;
        x = fmaf(x, 1.0f + C_ALPHA * C_DT, fmaf(t, dwv, t * (C_THETA * C_DT)));
        minx = fminf(minx, x);
        Wsum += dwv;
        float Rf = R0s * __builtin_amdgcn_exp2f(fmaf(CRW, Wsum, CRT * (float)NSTEP));
        float pf = p0 * __builtin_amdgcn_exp2f(fmaf(CPW, Wsum, CPT * (float)NSTEP));
        if (wv == 1) {
            size_t base = ((size_t)NSTEP * BATCH + b0 + l15) * 5;
            if (quad == 0) {
                f32x4a o = {x, Rf, pi, -pf};
                *(f32x4a*)(out + base) = o;
            } else if (quad == 1) {
                out[base + 4] = mdp0;
            }
        }
        if (wv == 0) {
            float xc = fmaxf(x, C_LOWER);
            float ux = Rf * rsqrtf(xc);           // R * xc^(gamma-1), gamma=0.5
            float uval = 2.0f * Rf * sqrtf(xc);   // R * xc^gamma / gamma
            float d = fmaxf(C_LOWER - minx, 0.0f);
            float pen = C_PEN * d * d;
            float t1 = pf + ux;
            float v1 = dpp_row_sum16(t1 * t1 + pen);
            float v2 = dpp_row_sum16(-uval + pen);
            if (lane == 0) {
                atomicAdd(&ws[3], v1);
                atomicAdd(&ws[4], v2);
                __threadfence();
                int old = atomicAdd((int*)(ws + 5), 1);
                if (old == NBLK - 1) {   // last block finalizes losses
                    float lp = atomicAdd(&ws[3], 0.0f) * (1.0f / (float)BATCH);
                    float lq = atomicAdd(&ws[4], 0.0f) * (1.0f / (float)BATCH);
                    out[(size_t)(NSTEP + 1) * BATCH * 5] = lp;
                    out[(size_t)(NSTEP + 1) * BATCH * 5 + 1] = lp + lq;
                }
            }
        }
    }
}

extern "C" void kernel_launch(void* const* d_in, const int* in_sizes, int n_in,
                              void* d_out, int out_size, void* d_ws, size_t ws_size,
                              hipStream_t stream) {
    const float* dw  = (const float*)d_in[0];
    const float* X0  = (const float*)d_in[1];
    const float* R0  = (const float*)d_in[2];
    const float* pW1 = (const float*)d_in[3];
    const float* pb1 = (const float*)d_in[4];
    const float* pW2 = (const float*)d_in[5];
    const float* pb2 = (const float*)d_in[6];
    const float* pW3 = (const float*)d_in[7];
    const float* pb3 = (const float*)d_in[8];
    const float* qW1 = (const float*)d_in[9];
    const float* qb1 = (const float*)d_in[10];
    const float* qW2 = (const float*)d_in[11];
    const float* qb2 = (const float*)d_in[12];
    const float* qW3 = (const float*)d_in[13];
    const float* qb3 = (const float*)d_in[14];
    float* out = (float*)d_out;
    float* ws  = (float*)d_ws;

    hipMemsetAsync(d_ws, 0, 64, stream);   // zero loss accumulators + block counter
    fused_kernel<<<NBLK, NT, 0, stream>>>(dw, X0, R0, pW1, pb1, pW2, pb2, pW3, pb3,
                                          qW1, qb1, qW2, qb2, qW3, qb3, ws, out);
}

// Round 4
// 205.562 us; speedup vs baseline: 1.0466x; 1.0043x over previous
//
#include <hip/hip_runtime.h>
#include <hip/hip_bf16.h>
#include <math.h>

#define NSTEP 100
#define BATCH 16384
#define MB 16            // samples per block == MFMA M
#define NBLK (BATCH/MB)  // 1024 blocks x 4 waves = 4096 waves -> 4/SIMD
#define NT 256

#define C_ALPHA 0.05f
#define C_SIGMA 0.2f
#define C_THETA 0.3f
#define C_DT    0.01f
#define C_LOWER 1e-6f
#define C_PEN   100.0f
#define LOG2E   1.4426950408889634f
#define TSCALE  (2.0f * LOG2E)      // tanh(z) = 1 - 2/(exp2(TSCALE*z)+1)
#define CRT ( 0.015f * C_DT * LOG2E)
#define CRW ( 0.1f * LOG2E)
#define CPT (-0.095f * C_DT * LOG2E)
#define CPW (-0.3f * LOG2E)

// Cross-wave LDS sync WITHOUT the vmcnt(0) drain __syncthreads() implies:
// only LDS ops must be complete/visible; global stores stay in flight.
#define WG_BARRIER() asm volatile("s_waitcnt lgkmcnt(0)\n\ts_barrier" ::: "memory")

typedef __attribute__((ext_vector_type(8))) short bf16x8;
typedef __attribute__((ext_vector_type(4))) float f32x4;
// 4-byte-aligned float4 for the packed out-row store (rows are 20B apart)
typedef __attribute__((ext_vector_type(4), aligned(4))) float f32x4a;

__device__ __forceinline__ float tanh_pre(float zs) {  // zs = TSCALE*z pre-folded
    float e = __builtin_amdgcn_exp2f(zs);
    return 1.0f - 2.0f * __builtin_amdgcn_rcpf(e + 1.0f);
}
__device__ __forceinline__ unsigned f2bf_u(float f) {  // RNE
    unsigned u = __float_as_uint(f);
    return (u + 0x7FFFu + ((u >> 16) & 1u)) >> 16;
}
__device__ __forceinline__ unsigned pack_bf16(float a, float b) {
    union { __hip_bfloat162 h; unsigned u; } cv;
    cv.h = __float22bfloat162_rn(make_float2(a, b));   // v_cvt_pk_bf16_f32
    return cv.u;
}
// sum across each 16-lane row via DPP row_ror butterfly; all lanes get the sum
__device__ __forceinline__ float dpp_row_sum16(float v) {
    int t;
    t = __builtin_amdgcn_update_dpp(0, __float_as_int(v), 0x128, 0xF, 0xF, true);
    v += __int_as_float(t);
    t = __builtin_amdgcn_update_dpp(0, __float_as_int(v), 0x124, 0xF, 0xF, true);
    v += __int_as_float(t);
    t = __builtin_amdgcn_update_dpp(0, __float_as_int(v), 0x122, 0xF, 0xF, true);
    v += __int_as_float(t);
    t = __builtin_amdgcn_update_dpp(0, __float_as_int(v), 0x121, 0xF, 0xF, true);
    v += __int_as_float(t);
    return v;
}

__global__ __launch_bounds__(NT, 4) void fused_kernel(
        const float* __restrict__ dw, const float* __restrict__ X0,
        const float* __restrict__ R0,
        const float* __restrict__ pW1, const float* __restrict__ pb1,
        const float* __restrict__ pW2, const float* __restrict__ pb2,
        const float* __restrict__ pW3, const float* __restrict__ pb3,
        const float* __restrict__ qW1, const float* __restrict__ qb1,
        const float* __restrict__ qW2, const float* __restrict__ qb2,
        const float* __restrict__ qW3, const float* __restrict__ qb3,
        float* __restrict__ ws, float* __restrict__ out) {
    __shared__ __align__(16) unsigned short sW2T[64 * 72];  // bf16 W2^T [n][k] *TSCALE
    __shared__ __align__(16) float sdw[MB * NSTEP];
    __shared__ __align__(16) uint2 sA2[2][2][64][2];  // [parity][kstep][lane][half]
    __shared__ __align__(16) float sP[2][4][16];      // [parity][wave][sample]

    const int tid = threadIdx.x;
    const int lane = tid & 63;
    const int wv = tid >> 6;               // wave role: kchunk owner + n-tile owner
    const int ks_own = wv >> 1;            // which kstep fragment this wave feeds
    const int half = wv & 1;               // which 8-byte half of that fragment
    const int b0 = blockIdx.x * MB;
    const int l15 = lane & 15, quad = lane >> 4;

    // ---- stage dw (coalesced float4) and W2^T (bf16, pre-scaled) ----
    {
        const float4* g = (const float4*)(dw + (size_t)b0 * NSTEP);
        float4* s = (float4*)sdw;
        for (int u = tid; u < MB * NSTEP / 4; u += NT) s[u] = g[u];
    }
    for (int u = tid; u < 4096; u += NT) {
        int k = u >> 6, n = u & 63;
        sW2T[n * 72 + k] = (unsigned short)f2bf_u(qW2[u] * TSCALE);
    }
    __syncthreads();

    // resident B fragments: this wave's single n-tile (nt = wv) x 2 k-steps
    bf16x8 Bf0, Bf1;
    {
        const unsigned short* r = &sW2T[(wv * 16 + l15) * 72 + quad * 8];
        Bf0 = *(const bf16x8*)r;
        Bf1 = *(const bf16x8*)(r + 32);
    }
    // layer-1 consts: this wave's 4 k's: k = ks_own*32 + quad*8 + half*4 + j
    float tco[4], w1xs[4], w1rs[4], b1s[4];
    {
        const int kb = ks_own * 32 + quad * 8 + half * 4;
        #pragma unroll
        for (int j = 0; j < 4; j++) {
            tco[j]  = qW1[kb + j] * (2.0f * C_DT * TSCALE);
            w1xs[j] = qW1[64 + kb + j] * TSCALE;
            w1rs[j] = qW1[128 + kb + j] * TSCALE;
            b1s[j]  = qb1[kb + j] * TSCALE;
        }
    }
    const float b2v = qb2[wv * 16 + l15] * TSCALE;
    const float w3v = qW3[wv * 16 + l15];
    const float b3 = qb3[0];
    const float X0v = X0[0], R0s = R0[0];

    // ---- p-net: p0, dp0 (one-time; computed redundantly per wave) ----
    float p0, dp0;
    {
        float pre = fmaf(pW1[64 + lane], X0v, fmaf(pW1[128 + lane], R0s, pb1[lane]));
        float h1 = tanh_pre(TSCALE * pre);
        float d1 = (1.0f - h1 * h1) * pW1[64 + lane];
        float a0 = pb2[lane], a1 = 0.f, a2 = 0.f, a3 = 0.f;
        float e0 = 0.f, e1 = 0.f, e2 = 0.f, e3 = 0.f;
        for (int i2 = 0; i2 < 64; i2 += 4) {
            float w0 = pW2[(i2 + 0) * 64 + lane];
            float w1 = pW2[(i2 + 1) * 64 + lane];
            float w2 = pW2[(i2 + 2) * 64 + lane];
            float w3 = pW2[(i2 + 3) * 64 + lane];
            a0 = fmaf(__shfl(h1, i2 + 0), w0, a0); e0 = fmaf(__shfl(d1, i2 + 0), w0, e0);
            a1 = fmaf(__shfl(h1, i2 + 1), w1, a1); e1 = fmaf(__shfl(d1, i2 + 1), w1, e1);
            a2 = fmaf(__shfl(h1, i2 + 2), w2, a2); e2 = fmaf(__shfl(d1, i2 + 2), w2, e2);
            a3 = fmaf(__shfl(h1, i2 + 3), w3, a3); e3 = fmaf(__shfl(d1, i2 + 3), w3, e3);
        }
        float pre2 = (a0 + a1) + (a2 + a3);
        float dpre2 = (e0 + e1) + (e2 + e3);
        float h2 = tanh_pre(TSCALE * pre2);
        float d2 = (1.0f - h2 * h2) * dpre2;
        float c1 = h2 * pW3[lane], c2 = d2 * pW3[lane];
        #pragma unroll
        for (int o = 1; o < 64; o <<= 1) {
            c1 += __shfl_xor(c1, o);
            c2 += __shfl_xor(c2, o);
        }
        p0 = c1 + pb3[0]; dp0 = c2;
    }
    const float mdp0 = -dp0;   // loop-invariant store source

    // ---- cooperative q-net: 4 waves split n 4-way & k 4-way ----
    auto qnet = [&](int par, float fi, float xv, float rv) -> float {
        union { uint2 u2; unsigned u[2]; } Aloc;
        {
            float z0 = fmaf(w1rs[0], rv, fmaf(w1xs[0], xv, fmaf(tco[0], fi, b1s[0])));
            float z1 = fmaf(w1rs[1], rv, fmaf(w1xs[1], xv, fmaf(tco[1], fi, b1s[1])));
            float z2 = fmaf(w1rs[2], rv, fmaf(w1xs[2], xv, fmaf(tco[2], fi, b1s[2])));
            float z3 = fmaf(w1rs[3], rv, fmaf(w1xs[3], xv, fmaf(tco[3], fi, b1s[3])));
            Aloc.u[0] = pack_bf16(tanh_pre(z0), tanh_pre(z1));
            Aloc.u[1] = pack_bf16(tanh_pre(z2), tanh_pre(z3));
        }
        sA2[par][ks_own][lane][half] = Aloc.u2;
        WG_BARRIER();                          // B1: all A half-fragments in LDS
        bf16x8 A0 = *(const bf16x8*)&sA2[par][0][lane][0];   // conflict-free b128
        bf16x8 A1 = *(const bf16x8*)&sA2[par][1][lane][0];
        f32x4 acc = {b2v, b2v, b2v, b2v};
        acc = __builtin_amdgcn_mfma_f32_16x16x32_bf16(A0, Bf0, acc, 0, 0, 0);
        acc = __builtin_amdgcn_mfma_f32_16x16x32_bf16(A1, Bf1, acc, 0, 0, 0);
        f32x4 part;
        #pragma unroll
        for (int r = 0; r < 4; r++)
            part[r] = dpp_row_sum16(tanh_pre(acc[r]) * w3v);
        if (l15 == 0) *(f32x4*)&sP[par][wv][quad * 4] = part;  // samples 4q+r
        WG_BARRIER();                          // B2: partials exchanged
        return ((sP[par][0][l15] + sP[par][1][l15]) +
                (sP[par][2][l15] + sP[par][3][l15])) + b3;
    };

    // ---- t=0 row + initial pi ----
    float x = X0v, Wsum = 0.0f, minx = X0v;
    float pi = qnet(0, 0.0f, X0v, R0s);
    if (wv == 3) {
        size_t base = (size_t)(b0 + l15) * 5;
        if (quad == 0) {
            f32x4a o = {X0v, R0s, pi, -p0};
            *(f32x4a*)(out + base) = o;
        } else if (quad == 1) {
            out[base + 4] = mdp0;
        }
    }

    float dw_next = sdw[l15 * NSTEP];
    #pragma unroll 1
    for (int i = 0; i < NSTEP - 1; i++) {
        const float fi = (float)(i + 1);
        float dwv = dw_next;
        dw_next = sdw[l15 * NSTEP + i + 1];
        float t = pi * C_SIGMA;
        x = fmaf(x, 1.0f + C_ALPHA * C_DT, fmaf(t, dwv, t * (C_THETA * C_DT)));
        minx = fminf(minx, x);
        Wsum += dwv;
        float R = R0s * __builtin_amdgcn_exp2f(fmaf(CRW, Wsum, CRT * fi));
        float pin = qnet((i + 1) & 1, fi, x, R);
        if (wv == 3) {                         // store duty + pm only on wave 3
            float pm = p0 * __builtin_amdgcn_exp2f(fmaf(CPW, Wsum, CPT * fi));
            size_t base = ((size_t)(i + 1) * BATCH + b0 + l15) * 5;
            if (quad == 0) {
                f32x4a o = {x, R, pin, -pm};
                *(f32x4a*)(out + base) = o;
            } else if (quad == 1) {
                out[base + 4] = mdp0;
            }
        }
        pi = pin;
    }

    // ---- final step (pi not updated) + losses ----
    {
        float dwv = dw_next;
        float t = pi * C_SIGMA;
        x = fmaf(x, 1.0f + C_ALPHA * C_DT, fmaf(t, dwv, t * (C_THETA * C_DT)));
        minx = fminf(minx, x);
        Wsum += dwv;
        float Rf = R0s * __builtin_amdgcn_exp2f(fmaf(CRW, Wsum, CRT * (float)NSTEP));
        float pf = p0 * __builtin_amdgcn_exp2f(fmaf(CPW, Wsum, CPT * (float)NSTEP));
        if (wv == 3) {
            size_t base = ((size_t)NSTEP * BATCH + b0 + l15) * 5;
            if (quad == 0) {
                f32x4a o = {x, Rf, pi, -pf};
                *(f32x4a*)(out + base) = o;
            } else if (quad == 1) {
                out[base + 4] = mdp0;
            }
        }
        if (wv == 0) {
            float xc = fmaxf(x, C_LOWER);
            float ux = Rf * rsqrtf(xc);           // R * xc^(gamma-1), gamma=0.5
            float uval = 2.0f * Rf * sqrtf(xc);   // R * xc^gamma / gamma
            float d = fmaxf(C_LOWER - minx, 0.0f);
            float pen = C_PEN * d * d;
            float t1 = pf + ux;
            float v1 = dpp_row_sum16(t1 * t1 + pen);
            float v2 = dpp_row_sum16(-uval + pen);
            if (lane == 0) {
                atomicAdd(&ws[3], v1);
                atomicAdd(&ws[4], v2);
                __threadfence();
                int old = atomicAdd((int*)(ws + 5), 1);
                if (old == NBLK - 1) {   // last block finalizes losses
                    float lp = atomicAdd(&ws[3], 0.0f) * (1.0f / (float)BATCH);
                    float lq = atomicAdd(&ws[4], 0.0f) * (1.0f / (float)BATCH);
                    out[(size_t)(NSTEP + 1) * BATCH * 5] = lp;
                    out[(size_t)(NSTEP + 1) * BATCH * 5 + 1] = lp + lq;
                }
            }
        }
    }
}

extern "C" void kernel_launch(void* const* d_in, const int* in_sizes, int n_in,
                              void* d_out, int out_size, void* d_ws, size_t ws_size,
                              hipStream_t stream) {
    const float* dw  = (const float*)d_in[0];
    const float* X0  = (const float*)d_in[1];
    const float* R0  = (const float*)d_in[2];
    const float* pW1 = (const float*)d_in[3];
    const float* pb1 = (const float*)d_in[4];
    const float* pW2 = (const float*)d_in[5];
    const float* pb2 = (const float*)d_in[6];
    const float* pW3 = (const float*)d_in[7];
    const float* pb3 = (const float*)d_in[8];
    const float* qW1 = (const float*)d_in[9];
    const float* qb1 = (const float*)d_in[10];
    const float* qW2 = (const float*)d_in[11];
    const float* qb2 = (const float*)d_in[12];
    const float* qW3 = (const float*)d_in[13];
    const float* qb3 = (const float*)d_in[14];
    float* out = (float*)d_out;
    float* ws  = (float*)d_ws;

    hipMemsetAsync(d_ws, 0, 64, stream);   // zero loss accumulators + block counter
    fused_kernel<<<NBLK, NT, 0, stream>>>(dw, X0, R0, pW1, pb1, pW2, pb2, pW3, pb3,
                                          qW1, qb1, qW2, qb2, qW3, qb3, ws, out);
}